// Round 2
// baseline (290.893 us; speedup 1.0000x reference)
//
#include <hip/hip_runtime.h>
#include <math.h>

#define IN_HW 76
#define HW2 (IN_HW*IN_HW)        // 5776
#define NA 3
#define NGT 50
#define NCLS 80
#define BATTRS 85
#define CELLS (NA*HW2)           // 17328
#define BLK 256
#define NYB ((CELLS + BLK - 1)/BLK)   // 68
#define NBS 32
#define NBLK (NBS*NYB)           // 2176

// Per-block partials: [5][NBLK] floats. Device global => no ws_size dependence,
// fully rewritten every launch (re-poison safe).
__device__ float g_partial[5 * NBLK];

__device__ __forceinline__ float sigm(float x) { return 1.0f / (1.0f + expf(-x)); }

__global__ __launch_bounds__(BLK) void yolo_main(const float* __restrict__ inp,
                                                 const float* __restrict__ tgt)
{
    const int b   = blockIdx.x;
    const int bid = blockIdx.x * NYB + blockIdx.y;
    const int tid = threadIdx.x;

    __shared__ float s_cx[NGT], s_cy[NGT], s_bw[NGT], s_bh[NGT];
    __shared__ float s_xmin[NGT], s_xmax[NGT], s_ymin[NGT], s_ymax[NGT], s_area[NGT];
    __shared__ int   s_code[NGT], s_cls[NGT];

    if (tid < NGT) {
        const float* g = tgt + ((size_t)b * NGT + tid) * 5;
        float cx = g[0] * (float)IN_HW;
        float cy = g[1] * (float)IN_HW;
        float bw = g[2] * (float)IN_HW;
        float bh = g[3] * (float)IN_HW;
        s_cx[tid] = cx; s_cy[tid] = cy; s_bw[tid] = bw; s_bh[tid] = bh;
        s_xmin[tid] = cx - bw * 0.5f; s_xmax[tid] = cx + bw * 0.5f;
        s_ymin[tid] = cy - bh * 0.5f; s_ymax[tid] = cy + bh * 0.5f;
        s_area[tid] = bw * bh;

        // best anchor over all 9 (bit-faithful to reference iou_xywh with
        // zero-centered boxes; IEEE f32 div; strict > => first-max like argmax)
        const float AW[9] = {12.f,19.f,40.f,36.f,76.f,72.f,142.f,192.f,459.f};
        const float AH[9] = {16.f,36.f,28.f,75.f,55.f,146.f,110.f,243.f,401.f};
        float bwh = bw * 0.5f, bhh = bh * 0.5f;
        float garea = bw * bh;
        float best = -1.0f; int bn = 0;
        #pragma unroll
        for (int a = 0; a < 9; a++) {
            float awh = AW[a] * 0.5f, ahh = AH[a] * 0.5f;
            float iw = fminf(bwh, awh) - fmaxf(-bwh, -awh); iw = fmaxf(iw, 0.0f);
            float ih = fminf(bhh, ahh) - fmaxf(-bhh, -ahh); ih = fmaxf(ih, 0.0f);
            float inter = iw * ih;
            float uni = garea + AW[a] * AH[a] - inter;
            float iou = inter / uni;
            if (iou > best) { best = iou; bn = a; }
        }
        int code = -1;
        if (bn < NA) {   // ANCHORS_MASK[2] = {0,1,2}
            int ii = (int)floorf(cx); ii = ii < 0 ? 0 : (ii > IN_HW-1 ? IN_HW-1 : ii);
            int jj = (int)floorf(cy); jj = jj < 0 ? 0 : (jj > IN_HW-1 ? IN_HW-1 : jj);
            code = bn * HW2 + jj * IN_HW + ii;
        }
        s_code[tid] = code;
        s_cls[tid]  = (int)g[4];
    }
    __syncthreads();

    float l_n = 0.f, l_loc = 0.f, l_cls = 0.f, l_cn = 0.f, l_cd = 0.f;
    const int cell = blockIdx.y * BLK + tid;
    if (cell < CELLS) {
        int a   = cell / HW2;
        int rem = cell - a * HW2;
        int j   = rem / IN_HW;
        int i   = rem - j * IN_HW;
        const float* base = inp + (size_t)(b * NA + a) * BATTRS * HW2 + rem;

        float zx = base[0];
        float zy = base[(size_t)1 * HW2];
        float zw = base[(size_t)2 * HW2];
        float zh = base[(size_t)3 * HW2];
        float zc = base[(size_t)4 * HW2];

        // scaled anchors for l=2: ANCHORS[0..2] / 8
        float saw = (a == 0) ? 1.5f : (a == 1 ? 2.375f : 5.0f);
        float sah = (a == 0) ? 2.0f : (a == 1 ? 4.5f   : 3.5f);

        float px = sigm(zx) + (float)i;
        float py = sigm(zy) + (float)j;
        float pw = expf(zw) * saw;
        float ph = expf(zh) * sah;
        float conf = sigm(zc);

        // assignment: last GT whose (best-anchor,cellj,celli) == this cell
        int at = -1;
        #pragma unroll
        for (int t = 0; t < NGT; t++) if (s_code[t] == cell) at = t;

        // ious vs all 50 GTs (noobj ignore mask)
        float pxmin = px - pw * 0.5f, pxmax = px + pw * 0.5f;
        float pymin = py - ph * 0.5f, pymax = py + ph * 0.5f;
        float parea = pw * ph;
        float iomax = -1e30f;
        #pragma unroll 5
        for (int t = 0; t < NGT; t++) {
            float iw = fminf(s_xmax[t], pxmax) - fmaxf(s_xmin[t], pxmin);
            float ih = fminf(s_ymax[t], pymax) - fmaxf(s_ymin[t], pymin);
            iw = fmaxf(iw, 0.f); ih = fmaxf(ih, 0.f);
            float inter = iw * ih;
            float iou = inter / (s_area[t] + parea - inter);
            iomax = fmaxf(iomax, iou);
        }

        float objf = (at >= 0) ? 1.f : 0.f;
        l_n = objf;

        bool sel = (at >= 0) || !(iomax > 0.5f);
        if (sel) {
            float p = fminf(fmaxf(conf, 1e-7f), 0.99999988f);
            l_cn = -(objf * logf(p) + (1.f - objf) * logf(1.f - p));
            l_cd = 1.f;
        }

        if (at >= 0) {
            float cx = s_cx[at], cy = s_cy[at], bw = s_bw[at], bh = s_bh[at];
            float b2xmin = s_xmin[at], b2xmax = s_xmax[at];
            float b2ymin = s_ymin[at], b2ymax = s_ymax[at];
            // box_ciou — replicate reference EXACTLY, including union = a1+a2+inter bug
            float iw = fmaxf(fminf(pxmax, b2xmax) - fmaxf(pxmin, b2xmin), 0.f);
            float ih = fmaxf(fminf(pymax, b2ymax) - fmaxf(pymin, b2ymin), 0.f);
            float inter = iw * ih;
            float uni = parea + bw * bh + inter;       // (sic) reference bug
            float iou = inter / uni;
            float dx = px - cx, dy = py - cy;
            float cdist = dx * dx + dy * dy;
            float ew = fmaxf(fmaxf(pxmax, b2xmax) - fminf(pxmin, b2xmin), 0.f);
            float eh = fmaxf(fmaxf(pymax, b2ymax) - fminf(pymin, b2ymin), 0.f);
            float diag = ew * ew + eh * eh;
            float ciou = iou - cdist / fmaxf(diag, 1e-6f);
            float dv = atanf(pw / fmaxf(ph, 1e-6f)) - atanf(bw / fmaxf(bh, 1e-6f));
            float v = 0.4052847345693511f * dv * dv;   // 4/pi^2
            float alpha = v / fmaxf(1.f - iou + v, 1e-6f);
            ciou -= alpha * v;
            l_loc = 1.f - ciou;

            // class BCE only where objf==1 (else multiplied by 0 => skip reads)
            int cls = s_cls[at];
            float s = 0.f;
            for (int c = 0; c < NCLS; c++) {
                float z = base[(size_t)(5 + c) * HW2];
                float p = sigm(z);
                p = fminf(fmaxf(p, 1e-7f), 0.99999988f);
                s += (c == cls) ? -logf(p) : -logf(1.f - p);
            }
            l_cls = s;
        }
    }

    // block reduction: wave shuffle then LDS across 4 waves
    float vals[5] = {l_n, l_loc, l_cls, l_cn, l_cd};
    #pragma unroll
    for (int c = 0; c < 5; c++) {
        float v = vals[c];
        #pragma unroll
        for (int off = 32; off >= 1; off >>= 1) v += __shfl_down(v, off, 64);
        vals[c] = v;
    }
    __shared__ float s_red[5][BLK / 64];
    int wave = tid >> 6, lane = tid & 63;
    if (lane == 0)
        for (int c = 0; c < 5; c++) s_red[c][wave] = vals[c];
    __syncthreads();
    if (tid == 0) {
        for (int c = 0; c < 5; c++) {
            float s = 0.f;
            for (int w = 0; w < BLK / 64; w++) s += s_red[c][w];
            g_partial[c * NBLK + bid] = s;
        }
    }
}

__global__ __launch_bounds__(256) void yolo_final(float* __restrict__ out)
{
    const int tid = threadIdx.x;
    double acc[5] = {0, 0, 0, 0, 0};
    for (int idx = tid; idx < NBLK; idx += 256) {
        #pragma unroll
        for (int c = 0; c < 5; c++) acc[c] += (double)g_partial[c * NBLK + idx];
    }
    #pragma unroll
    for (int c = 0; c < 5; c++) {
        double v = acc[c];
        #pragma unroll
        for (int off = 32; off >= 1; off >>= 1) v += __shfl_down(v, off, 64);
        acc[c] = v;
    }
    __shared__ double s_red[5][4];
    int wave = tid >> 6, lane = tid & 63;
    if (lane == 0)
        for (int c = 0; c < 5; c++) s_red[c][wave] = acc[c];
    __syncthreads();
    if (tid == 0) {
        double n = 0, loc = 0, cls = 0, cn = 0, cd = 0;
        for (int w = 0; w < 4; w++) {
            n += s_red[0][w]; loc += s_red[1][w]; cls += s_red[2][w];
            cn += s_red[3][w]; cd += s_red[4][w];
        }
        float nf  = fmaxf((float)n, 1.0f);
        float has = (n > 0.0) ? 1.f : 0.f;
        float loss = has * ((float)loc / nf * 0.05f + (float)cls / (nf * 80.0f) * 1.0f);
        float lconf = (float)cn / fmaxf((float)cd, 1.f);
        // BALANCE[2] * OBJ_RATIO = 4.0 * 5*608^2/416^2
        loss += lconf * (float)(4.0 * 5.0 * (608.0 * 608.0) / (416.0 * 416.0));
        out[0] = loss;
    }
}

extern "C" void kernel_launch(void* const* d_in, const int* in_sizes, int n_in,
                              void* d_out, int out_size, void* d_ws, size_t ws_size,
                              hipStream_t stream)
{
    // d_in[0] = l (always 2 for this problem), d_in[1] = input, d_in[2] = targets
    const float* inp = (const float*)d_in[1];
    const float* tgt = (const float*)d_in[2];
    dim3 grid(NBS, NYB);
    yolo_main<<<grid, BLK, 0, stream>>>(inp, tgt);
    yolo_final<<<1, 256, 0, stream>>>((float*)d_out);
}

// Round 6
// 290.075 us; speedup vs baseline: 1.0028x; 1.0028x over previous
//
#include <hip/hip_runtime.h>
#include <math.h>

#define IN_HW 76
#define HW2 (IN_HW*IN_HW)        // 5776
#define NA 3
#define NGT 50
#define NCLS 80
#define BATTRS 85
#define CELLS (NA*HW2)           // 17328
#define BLK 256
#define NYB ((CELLS + BLK - 1)/BLK)   // 68
#define NBS 32
#define NBLK (NBS*NYB)           // 2176

// Per-block partials: [5][NBLK] floats. Device global => no ws_size dependence,
// fully rewritten every launch (re-poison safe).
__device__ float g_partial[5 * NBLK];

__device__ __forceinline__ float sigm(float x) { return 1.0f / (1.0f + expf(-x)); }

__global__ __launch_bounds__(BLK) void yolo_main(const float* __restrict__ inp,
                                                 const float* __restrict__ tgt)
{
    const int b   = blockIdx.x;
    const int bid = blockIdx.x * NYB + blockIdx.y;
    const int tid = threadIdx.x;

    __shared__ float s_cx[NGT], s_cy[NGT], s_bw[NGT], s_bh[NGT];
    __shared__ float s_xmin[NGT], s_xmax[NGT], s_ymin[NGT], s_ymax[NGT], s_area[NGT];
    __shared__ int   s_code[NGT], s_cls[NGT];

    if (tid < NGT) {
        const float* g = tgt + ((size_t)b * NGT + tid) * 5;
        float cx = g[0] * (float)IN_HW;
        float cy = g[1] * (float)IN_HW;
        float bw = g[2] * (float)IN_HW;
        float bh = g[3] * (float)IN_HW;
        s_cx[tid] = cx; s_cy[tid] = cy; s_bw[tid] = bw; s_bh[tid] = bh;
        s_xmin[tid] = cx - bw * 0.5f; s_xmax[tid] = cx + bw * 0.5f;
        s_ymin[tid] = cy - bh * 0.5f; s_ymax[tid] = cy + bh * 0.5f;
        s_area[tid] = bw * bh;

        // best anchor over all 9 (bit-faithful to reference iou_xywh with
        // zero-centered boxes; IEEE f32 div; strict > => first-max like argmax)
        const float AW[9] = {12.f,19.f,40.f,36.f,76.f,72.f,142.f,192.f,459.f};
        const float AH[9] = {16.f,36.f,28.f,75.f,55.f,146.f,110.f,243.f,401.f};
        float bwh = bw * 0.5f, bhh = bh * 0.5f;
        float garea = bw * bh;
        float best = -1.0f; int bn = 0;
        #pragma unroll
        for (int a = 0; a < 9; a++) {
            float awh = AW[a] * 0.5f, ahh = AH[a] * 0.5f;
            float iw = fminf(bwh, awh) - fmaxf(-bwh, -awh); iw = fmaxf(iw, 0.0f);
            float ih = fminf(bhh, ahh) - fmaxf(-bhh, -ahh); ih = fmaxf(ih, 0.0f);
            float inter = iw * ih;
            float uni = garea + AW[a] * AH[a] - inter;
            float iou = inter / uni;
            if (iou > best) { best = iou; bn = a; }
        }
        int code = -1;
        if (bn < NA) {   // ANCHORS_MASK[2] = {0,1,2}
            int ii = (int)floorf(cx); ii = ii < 0 ? 0 : (ii > IN_HW-1 ? IN_HW-1 : ii);
            int jj = (int)floorf(cy); jj = jj < 0 ? 0 : (jj > IN_HW-1 ? IN_HW-1 : jj);
            code = bn * HW2 + jj * IN_HW + ii;
        }
        s_code[tid] = code;
        s_cls[tid]  = (int)g[4];
    }
    __syncthreads();

    float l_n = 0.f, l_loc = 0.f, l_cls = 0.f, l_cn = 0.f, l_cd = 0.f;
    const int cell = blockIdx.y * BLK + tid;
    if (cell < CELLS) {
        int a   = cell / HW2;
        int rem = cell - a * HW2;
        int j   = rem / IN_HW;
        int i   = rem - j * IN_HW;
        const float* base = inp + (size_t)(b * NA + a) * BATTRS * HW2 + rem;

        float zx = base[0];
        float zy = base[(size_t)1 * HW2];
        float zw = base[(size_t)2 * HW2];
        float zh = base[(size_t)3 * HW2];
        float zc = base[(size_t)4 * HW2];

        // scaled anchors for l=2: ANCHORS[0..2] / 8
        float saw = (a == 0) ? 1.5f : (a == 1 ? 2.375f : 5.0f);
        float sah = (a == 0) ? 2.0f : (a == 1 ? 4.5f   : 3.5f);

        float px = sigm(zx) + (float)i;
        float py = sigm(zy) + (float)j;
        float pw = expf(zw) * saw;
        float ph = expf(zh) * sah;
        float conf = sigm(zc);

        // assignment: last GT whose (best-anchor,cellj,celli) == this cell
        int at = -1;
        #pragma unroll
        for (int t = 0; t < NGT; t++) if (s_code[t] == cell) at = t;

        // ious vs all 50 GTs (noobj ignore mask)
        float pxmin = px - pw * 0.5f, pxmax = px + pw * 0.5f;
        float pymin = py - ph * 0.5f, pymax = py + ph * 0.5f;
        float parea = pw * ph;
        float iomax = -1e30f;
        #pragma unroll 5
        for (int t = 0; t < NGT; t++) {
            float iw = fminf(s_xmax[t], pxmax) - fmaxf(s_xmin[t], pxmin);
            float ih = fminf(s_ymax[t], pymax) - fmaxf(s_ymin[t], pymin);
            iw = fmaxf(iw, 0.f); ih = fmaxf(ih, 0.f);
            float inter = iw * ih;
            float iou = inter / (s_area[t] + parea - inter);
            iomax = fmaxf(iomax, iou);
        }

        float objf = (at >= 0) ? 1.f : 0.f;
        l_n = objf;

        bool sel = (at >= 0) || !(iomax > 0.5f);
        if (sel) {
            float p = fminf(fmaxf(conf, 1e-7f), 0.99999988f);
            l_cn = -(objf * logf(p) + (1.f - objf) * logf(1.f - p));
            l_cd = 1.f;
        }

        if (at >= 0) {
            float cx = s_cx[at], cy = s_cy[at], bw = s_bw[at], bh = s_bh[at];
            float b2xmin = s_xmin[at], b2xmax = s_xmax[at];
            float b2ymin = s_ymin[at], b2ymax = s_ymax[at];
            // box_ciou — replicate reference EXACTLY, including union = a1+a2+inter bug
            float iw = fmaxf(fminf(pxmax, b2xmax) - fmaxf(pxmin, b2xmin), 0.f);
            float ih = fmaxf(fminf(pymax, b2ymax) - fmaxf(pymin, b2ymin), 0.f);
            float inter = iw * ih;
            float uni = parea + bw * bh + inter;       // (sic) reference bug
            float iou = inter / uni;
            float dx = px - cx, dy = py - cy;
            float cdist = dx * dx + dy * dy;
            float ew = fmaxf(fmaxf(pxmax, b2xmax) - fminf(pxmin, b2xmin), 0.f);
            float eh = fmaxf(fmaxf(pymax, b2ymax) - fminf(pymin, b2ymin), 0.f);
            float diag = ew * ew + eh * eh;
            float ciou = iou - cdist / fmaxf(diag, 1e-6f);
            float dv = atanf(pw / fmaxf(ph, 1e-6f)) - atanf(bw / fmaxf(bh, 1e-6f));
            float v = 0.4052847345693511f * dv * dv;   // 4/pi^2
            float alpha = v / fmaxf(1.f - iou + v, 1e-6f);
            ciou -= alpha * v;
            l_loc = 1.f - ciou;

            // class BCE only where objf==1 (else multiplied by 0 => skip reads)
            int cls = s_cls[at];
            float s = 0.f;
            for (int c = 0; c < NCLS; c++) {
                float z = base[(size_t)(5 + c) * HW2];
                float p = sigm(z);
                p = fminf(fmaxf(p, 1e-7f), 0.99999988f);
                s += (c == cls) ? -logf(p) : -logf(1.f - p);
            }
            l_cls = s;
        }
    }

    // block reduction: wave shuffle then LDS across 4 waves
    float vals[5] = {l_n, l_loc, l_cls, l_cn, l_cd};
    #pragma unroll
    for (int c = 0; c < 5; c++) {
        float v = vals[c];
        #pragma unroll
        for (int off = 32; off >= 1; off >>= 1) v += __shfl_down(v, off, 64);
        vals[c] = v;
    }
    __shared__ float s_red[5][BLK / 64];
    int wave = tid >> 6, lane = tid & 63;
    if (lane == 0)
        for (int c = 0; c < 5; c++) s_red[c][wave] = vals[c];
    __syncthreads();
    if (tid == 0) {
        for (int c = 0; c < 5; c++) {
            float s = 0.f;
            for (int w = 0; w < BLK / 64; w++) s += s_red[c][w];
            g_partial[c * NBLK + bid] = s;
        }
    }
}

__global__ __launch_bounds__(256) void yolo_final(float* __restrict__ out)
{
    const int tid = threadIdx.x;
    double acc[5] = {0, 0, 0, 0, 0};
    for (int idx = tid; idx < NBLK; idx += 256) {
        #pragma unroll
        for (int c = 0; c < 5; c++) acc[c] += (double)g_partial[c * NBLK + idx];
    }
    #pragma unroll
    for (int c = 0; c < 5; c++) {
        double v = acc[c];
        #pragma unroll
        for (int off = 32; off >= 1; off >>= 1) v += __shfl_down(v, off, 64);
        acc[c] = v;
    }
    __shared__ double s_red[5][4];
    int wave = tid >> 6, lane = tid & 63;
    if (lane == 0)
        for (int c = 0; c < 5; c++) s_red[c][wave] = acc[c];
    __syncthreads();
    if (tid == 0) {
        double n = 0, loc = 0, cls = 0, cn = 0, cd = 0;
        for (int w = 0; w < 4; w++) {
            n += s_red[0][w]; loc += s_red[1][w]; cls += s_red[2][w];
            cn += s_red[3][w]; cd += s_red[4][w];
        }
        float nf  = fmaxf((float)n, 1.0f);
        float has = (n > 0.0) ? 1.f : 0.f;
        float loss = has * ((float)loc / nf * 0.05f + (float)cls / (nf * 80.0f) * 1.0f);
        float lconf = (float)cn / fmaxf((float)cd, 1.f);
        // BALANCE[2] * OBJ_RATIO = 4.0 * 5*608^2/416^2
        loss += lconf * (float)(4.0 * 5.0 * (608.0 * 608.0) / (416.0 * 416.0));
        out[0] = loss;
    }
}

extern "C" void kernel_launch(void* const* d_in, const int* in_sizes, int n_in,
                              void* d_out, int out_size, void* d_ws, size_t ws_size,
                              hipStream_t stream)
{
    // d_in[0] = l (always 2 for this problem), d_in[1] = input, d_in[2] = targets
    const float* inp = (const float*)d_in[1];
    const float* tgt = (const float*)d_in[2];
    dim3 grid(NBS, NYB);
    yolo_main<<<grid, BLK, 0, stream>>>(inp, tgt);
    yolo_final<<<1, 256, 0, stream>>>((float*)d_out);
}